// Round 1
// baseline (624.398 us; speedup 1.0000x reference)
//
#include <hip/hip_runtime.h>
#include <hip/hip_cooperative_groups.h>

namespace cg = cooperative_groups;

// SetNorm: B=64, N=2048, D=256 fp32.
// out[b,n,d] = n < len[b] ? ((x[b,n,d] - mean_b) / (sqrt(var_b) + eps)) * w[d] + bias[d] : 0
//
// R5: single cooperative kernel. 2048 blocks (one per (batch, 64-row chunk)),
// co-resident at 8 blocks/CU. Invalid chunks zero-fill BEFORE grid.sync
// (overlaps zero-writes with valid blocks' stat reads), valid chunks compute
// partials -> grid.sync -> re-reduce 32 partials (L2-hot) -> normalize the
// SAME chunk (phase-B x re-read has same-XCD L2 affinity). Fallback to the
// verified 2-kernel path if cooperative launch is unavailable.

#define BB 64
#define NN 2048
#define DD 256
#define EPSV 1e-5f
#define CHUNKS 32
#define ROWS_PER_CHUNK (NN / CHUNKS) // 64
#define NBLOCKS (BB * CHUNKS)        // 2048

typedef float f32x4 __attribute__((ext_vector_type(4)));

// ---------------- fused cooperative kernel ----------------
__global__ __launch_bounds__(256, 8) void setnorm_fused(
    const float* __restrict__ x, const int* __restrict__ lengths,
    const float* __restrict__ weights, const float* __restrict__ biases,
    float* __restrict__ partials, float* __restrict__ out) {
  const int blk = blockIdx.x;
  const int b = blk >> 5;  // 32 chunks per batch
  const int c = blk & 31;
  const int len = lengths[b];
  const int rowBase = c * ROWS_PER_CHUNK;
  const size_t chunkBase4 = ((size_t)b * NN + (size_t)rowBase) * (DD / 4);

  int validRows = len - rowBase;
  if (validRows > ROWS_PER_CHUNK) validRows = ROWS_PER_CHUNK;

  if (validRows <= 0) {
    // Fully-invalid chunk: zero-fill now so the writes overlap other blocks'
    // phase-A reads; then just participate in the grid barrier and exit.
    const f32x4 z = {0.f, 0.f, 0.f, 0.f};
    f32x4* po = (f32x4*)out + chunkBase4;
    #pragma unroll 4
    for (int k = 0; k < 16; ++k)
      __builtin_nontemporal_store(z, po + k * 256 + threadIdx.x);
    cg::this_grid().sync();
    return;
  }

  // ---- Phase A: partial sum / sumsq over this chunk's valid rows ----
  float sum = 0.f, sumsq = 0.f;
  {
    const f32x4* p = (const f32x4*)x + chunkBase4;
    const int n4 = validRows * (DD / 4); // <= 4096
    for (int i = threadIdx.x; i < n4; i += 512) {
      f32x4 v = p[i];
      sum += v.x + v.y + v.z + v.w;
      sumsq += v.x * v.x + v.y * v.y + v.z * v.z + v.w * v.w;
      const int j = i + 256;
      if (j < n4) {
        f32x4 u = p[j];
        sum += u.x + u.y + u.z + u.w;
        sumsq += u.x * u.x + u.y * u.y + u.z * u.z + u.w * u.w;
      }
    }
  }
  #pragma unroll
  for (int off = 32; off > 0; off >>= 1) {
    sum += __shfl_down(sum, off, 64);
    sumsq += __shfl_down(sumsq, off, 64);
  }
  __shared__ float ssum[4], ssq[4];
  {
    const int wave = threadIdx.x >> 6;
    const int lane = threadIdx.x & 63;
    if (lane == 0) { ssum[wave] = sum; ssq[wave] = sumsq; }
  }
  __syncthreads();
  if (threadIdx.x == 0) {
    const float ts = ssum[0] + ssum[1] + ssum[2] + ssum[3];
    const float tq = ssq[0] + ssq[1] + ssq[2] + ssq[3];
    partials[blk * 2 + 0] = ts;
    partials[blk * 2 + 1] = tq;
  }
  __threadfence(); // make partials device-visible before the grid barrier
  cg::this_grid().sync();

  // ---- Phase B: finalize stats (re-reduce this batch's partials) ----
  __shared__ float s_mean, s_inv;
  if (threadIdx.x < 64) {
    float s = 0.f, q = 0.f;
    // only chunks with at least one valid row wrote partials
    if (threadIdx.x < CHUNKS && threadIdx.x * ROWS_PER_CHUNK < len) {
      s = partials[(b * CHUNKS + threadIdx.x) * 2 + 0];
      q = partials[(b * CHUNKS + threadIdx.x) * 2 + 1];
    }
    #pragma unroll
    for (int off = 16; off > 0; off >>= 1) {
      s += __shfl_down(s, off, 64);
      q += __shfl_down(q, off, 64);
    }
    if (threadIdx.x == 0) {
      const float denom = (float)len * (float)DD;
      const float mean = s / denom;
      float var = q / denom - mean * mean;
      var = fmaxf(var, 0.f);
      s_mean = mean;
      s_inv = 1.f / (sqrtf(var) + EPSV);
    }
  }
  __syncthreads();
  const float mean = s_mean;
  const float inv = s_inv;

  // ---- normalize the same chunk (x re-read is L2/L3-hot) ----
  const int d4 = threadIdx.x & 63; // iteration-invariant feature index
  const f32x4 w = ((const f32x4*)weights)[d4];
  const f32x4 bi = ((const f32x4*)biases)[d4];
  const int rowT = rowBase + (threadIdx.x >> 6);

  const f32x4* px = (const f32x4*)x + chunkBase4;
  f32x4* po = (f32x4*)out + chunkBase4;
  #pragma unroll 4
  for (int k = 0; k < 16; ++k) {
    const int i = k * 256 + threadIdx.x;
    const int row = rowT + k * 4; // 256 f32x4 = 4 rows per step
    f32x4 o = {0.f, 0.f, 0.f, 0.f};
    if (row < len) {
      const f32x4 v = px[i];
      o.x = (v.x - mean) * inv * w.x + bi.x;
      o.y = (v.y - mean) * inv * w.y + bi.y;
      o.z = (v.z - mean) * inv * w.z + bi.z;
      o.w = (v.w - mean) * inv * w.w + bi.w;
    }
    __builtin_nontemporal_store(o, po + i);
  }
}

// ---------------- fallback: verified 2-kernel path ----------------
__global__ __launch_bounds__(256) void setnorm_partials(
    const float* __restrict__ x, const int* __restrict__ lengths,
    float* __restrict__ partials) {
  const int c = blockIdx.x;
  const int b = blockIdx.y;
  const int len = lengths[b];
  const int rowBase = c * ROWS_PER_CHUNK;
  int validRows = len - rowBase;
  if (validRows > ROWS_PER_CHUNK) validRows = ROWS_PER_CHUNK;

  float sum = 0.f, sumsq = 0.f;
  if (validRows > 0) {
    const f32x4* p =
        (const f32x4*)(x + ((size_t)b * NN + (size_t)rowBase) * DD);
    const int n4 = validRows * (DD / 4);
    for (int i = threadIdx.x; i < n4; i += 512) {
      f32x4 v = p[i];
      sum += v.x + v.y + v.z + v.w;
      sumsq += v.x * v.x + v.y * v.y + v.z * v.z + v.w * v.w;
      const int j = i + 256;
      if (j < n4) {
        f32x4 u = p[j];
        sum += u.x + u.y + u.z + u.w;
        sumsq += u.x * u.x + u.y * u.y + u.z * u.z + u.w * u.w;
      }
    }
  }
  #pragma unroll
  for (int off = 32; off > 0; off >>= 1) {
    sum += __shfl_down(sum, off, 64);
    sumsq += __shfl_down(sumsq, off, 64);
  }
  __shared__ float ssum[4], ssq[4];
  const int wave = threadIdx.x >> 6;
  const int lane = threadIdx.x & 63;
  if (lane == 0) { ssum[wave] = sum; ssq[wave] = sumsq; }
  __syncthreads();
  if (threadIdx.x == 0) {
    float ts = 0.f, tq = 0.f;
    #pragma unroll
    for (int w = 0; w < 4; ++w) { ts += ssum[w]; tq += ssq[w]; }
    partials[(b * CHUNKS + c) * 2 + 0] = ts;
    partials[(b * CHUNKS + c) * 2 + 1] = tq;
  }
}

__global__ __launch_bounds__(256) void setnorm_norm(
    const float* __restrict__ x, const int* __restrict__ lengths,
    const float* __restrict__ weights, const float* __restrict__ biases,
    const float* __restrict__ partials, float* __restrict__ out) {
  const int blockBase = blockIdx.x * 1024;
  const int b = blockBase >> 17;
  const int row0 = (blockBase & 131071) >> 6;
  const int len = lengths[b];

  if (row0 >= len) {
    const f32x4 z = {0.f, 0.f, 0.f, 0.f};
    #pragma unroll
    for (int i = 0; i < 4; ++i)
      __builtin_nontemporal_store(z,
          ((f32x4*)out) + blockBase + i * 256 + threadIdx.x);
    return;
  }

  __shared__ float s_mean, s_inv;
  if (threadIdx.x < 64) {
    float s = 0.f, q = 0.f;
    if (threadIdx.x < CHUNKS) {
      s = partials[(b * CHUNKS + threadIdx.x) * 2 + 0];
      q = partials[(b * CHUNKS + threadIdx.x) * 2 + 1];
    }
    #pragma unroll
    for (int off = 16; off > 0; off >>= 1) {
      s += __shfl_down(s, off, 64);
      q += __shfl_down(q, off, 64);
    }
    if (threadIdx.x == 0) {
      const float denom = (float)lengths[b] * (float)DD;
      const float mean = s / denom;
      float var = q / denom - mean * mean;
      var = fmaxf(var, 0.f);
      s_mean = mean;
      s_inv = 1.f / (sqrtf(var) + EPSV);
    }
  }
  __syncthreads();
  const float mean = s_mean;
  const float inv = s_inv;

  const int d4 = threadIdx.x & 63;
  const f32x4 w = ((const f32x4*)weights)[d4];
  const f32x4 bi = ((const f32x4*)biases)[d4];
  const int rowT = row0 + (threadIdx.x >> 6);

  #pragma unroll
  for (int i = 0; i < 4; ++i) {
    const int idx4 = blockBase + i * 256 + threadIdx.x;
    const int row = rowT + i * 4;
    f32x4 o = {0.f, 0.f, 0.f, 0.f};
    if (row < len) {
      const f32x4 v = ((const f32x4*)x)[idx4];
      o.x = (v.x - mean) * inv * w.x + bi.x;
      o.y = (v.y - mean) * inv * w.y + bi.y;
      o.z = (v.z - mean) * inv * w.z + bi.z;
      o.w = (v.w - mean) * inv * w.w + bi.w;
    }
    __builtin_nontemporal_store(o, ((f32x4*)out) + idx4);
  }
}

extern "C" void kernel_launch(void* const* d_in, const int* in_sizes, int n_in,
                              void* d_out, int out_size, void* d_ws, size_t ws_size,
                              hipStream_t stream) {
  const float* x = (const float*)d_in[0];
  const int* lengths = (const int*)d_in[1];
  const float* weights = (const float*)d_in[2];
  const float* biases = (const float*)d_in[3];
  float* out = (float*)d_out;
  float* partials = (float*)d_ws; // B*CHUNKS*2 floats = 16 KB

  void* args[] = {(void*)&x, (void*)&lengths, (void*)&weights,
                  (void*)&biases, (void*)&partials, (void*)&out};
  const hipError_t err = hipLaunchCooperativeKernel(
      (const void*)setnorm_fused, dim3(NBLOCKS), dim3(256), args, 0, stream);
  if (err != hipSuccess) {
    // fallback: verified two-kernel path
    dim3 g1(CHUNKS, BB);
    setnorm_partials<<<g1, 256, 0, stream>>>(x, lengths, partials);
    const int total4 = BB * NN * DD / 4; // 8388608 f32x4
    setnorm_norm<<<total4 / 1024, 256, 0, stream>>>(x, lengths, weights,
                                                    biases, partials, out);
  }
}

// Round 3
// 226.620 us; speedup vs baseline: 2.7553x; 2.7553x over previous
//
#include <hip/hip_runtime.h>

// SetNorm: B=64, N=2048, D=256 fp32.
// out[b,n,d] = n < len[b] ? ((x[b,n,d] - mean_b) / (sqrt(var_b) + eps)) * w[d] + bias[d] : 0
//
// R7 (= R6 resubmit after infra failure, + workspace overlay).
// Multi-kernel (cooperative grid-sync was 7x slower: sync storm).
// Key change vs R4 baseline: LOAD-BALANCED striped row-group assignment.
// Dispatch puts blocks strided by ~256 on the same CU; with contiguous chunks
// that aliases to "same chunk index / same row range" -> some CUs get all-valid
// work, others none (K1 and K2 both ran ~2x their mean). Now each block's
// 4-row groups are strided across the whole batch, so per-block valid work is
// ~len/N regardless of block index. Stats finalize hoisted to a tiny kernel;
// finalized (mean, inv) overlaid into chunk-0 partial slots so total
// workspace stays 16 KB.

#define BB 64
#define NN 2048
#define DD 256
#define EPSV 1e-5f
#define CHUNKS 32                 // K1 blocks per batch
#define GROUPS (NN / 4)           // 512 4-row groups per batch
#define BAT4 (NN * DD / 4)        // 131072 f32x4 per batch
#define K2_BPB (GROUPS / 4)       // 128 K2 blocks per batch (4 groups each)

typedef float f32x4 __attribute__((ext_vector_type(4)));

// ---------- Kernel 1: partial sum/sumsq, striped groups ----------
// chunk c of batch b handles 4-row groups g = c + 32*k, k = 0..15.
// Valid-group count ~= len/128 for every chunk -> balanced.
__global__ __launch_bounds__(256) void setnorm_partials(
    const float* __restrict__ x, const int* __restrict__ lengths,
    float* __restrict__ partials) {
  const int c = blockIdx.x;
  const int b = blockIdx.y;
  const int len = lengths[b];
  const int tRow = threadIdx.x >> 6;     // row within group (0..3)
  const int g4 = (len + 3) >> 2;         // # groups with >=1 valid row
  int nk = (g4 - c + 31) >> 5;           // # of this chunk's groups to touch
  if (nk < 0) nk = 0;

  float sum = 0.f, sumsq = 0.f;
  const f32x4* px = (const f32x4*)x + (size_t)b * BAT4;
  #pragma unroll 4
  for (int k = 0; k < nk; ++k) {
    const int g = c + (k << 5);          // g <= 511 guaranteed by nk
    const f32x4 v = px[g * 256 + threadIdx.x];   // unconditional, in-bounds
    const int row = (g << 2) + tRow;
    if (row < len) {                     // mask accumulate (partial last group)
      sum += v.x + v.y + v.z + v.w;
      sumsq += v.x * v.x + v.y * v.y + v.z * v.z + v.w * v.w;
    }
  }
  #pragma unroll
  for (int off = 32; off > 0; off >>= 1) {
    sum += __shfl_down(sum, off, 64);
    sumsq += __shfl_down(sumsq, off, 64);
  }
  __shared__ float ssum[4], ssq[4];
  const int wave = threadIdx.x >> 6;
  const int lane = threadIdx.x & 63;
  if (lane == 0) { ssum[wave] = sum; ssq[wave] = sumsq; }
  __syncthreads();
  if (threadIdx.x == 0) {
    const float ts = ssum[0] + ssum[1] + ssum[2] + ssum[3];
    const float tq = ssq[0] + ssq[1] + ssq[2] + ssq[3];
    partials[(b * CHUNKS + c) * 2 + 0] = ts;
    partials[(b * CHUNKS + c) * 2 + 1] = tq;
  }
}

// ---------- Kernel 1.5: finalize per-batch stats (64 blocks x 64 thr) ----------
// Writes (mean, inv) into chunk-0's partial slots (safe: the store's data
// depends via the shuffle chain on all 32 loads, so reads precede the write).
__global__ __launch_bounds__(64) void setnorm_finalize(
    const int* __restrict__ lengths, float* __restrict__ partials) {
  const int b = blockIdx.x;
  float s = 0.f, q = 0.f;
  if (threadIdx.x < CHUNKS) {
    s = partials[(b * CHUNKS + threadIdx.x) * 2 + 0];
    q = partials[(b * CHUNKS + threadIdx.x) * 2 + 1];
  }
  #pragma unroll
  for (int off = 16; off > 0; off >>= 1) {
    s += __shfl_down(s, off, 64);
    q += __shfl_down(q, off, 64);
  }
  if (threadIdx.x == 0) {
    const float denom = (float)lengths[b] * (float)DD;
    const float mean = s / denom;
    float var = q / denom - mean * mean;
    var = fmaxf(var, 0.f);
    partials[b * CHUNKS * 2 + 0] = mean;
    partials[b * CHUNKS * 2 + 1] = 1.f / (sqrtf(var) + EPSV);
  }
}

// ---------- Kernel 2: normalize, striped groups ----------
// block (b, j) handles groups g = j + 128*i, i = 0..3. Valid fraction ~len/N
// for every block; row = 4g + waveId -> validity is wave-uniform.
__global__ __launch_bounds__(256) void setnorm_norm(
    const float* __restrict__ x, const int* __restrict__ lengths,
    const float* __restrict__ weights, const float* __restrict__ biases,
    const float* __restrict__ partials, float* __restrict__ out) {
  const int blk = blockIdx.x;
  const int b = blk >> 7;                // 128 blocks per batch
  const int j = blk & 127;
  const int len = lengths[b];
  const float mean = partials[b * CHUNKS * 2 + 0];  // uniform -> scalar load
  const float inv = partials[b * CHUNKS * 2 + 1];

  const int d4 = threadIdx.x & 63;       // feature f32x4 index
  const f32x4 w = ((const f32x4*)weights)[d4];
  const f32x4 bi = ((const f32x4*)biases)[d4];
  const int tRow = threadIdx.x >> 6;

  const f32x4* px = (const f32x4*)x + (size_t)b * BAT4;
  f32x4* po = (f32x4*)out + (size_t)b * BAT4;
  #pragma unroll
  for (int i = 0; i < 4; ++i) {
    const int g = j + (i << 7);          // strided group
    const int idx4 = g * 256 + threadIdx.x;
    const int row = (g << 2) + tRow;     // wave-uniform validity
    f32x4 o = {0.f, 0.f, 0.f, 0.f};
    if (row < len) {
      const f32x4 v = px[idx4];
      o.x = (v.x - mean) * inv * w.x + bi.x;
      o.y = (v.y - mean) * inv * w.y + bi.y;
      o.z = (v.z - mean) * inv * w.z + bi.z;
      o.w = (v.w - mean) * inv * w.w + bi.w;
    }
    __builtin_nontemporal_store(o, po + idx4);
  }
}

extern "C" void kernel_launch(void* const* d_in, const int* in_sizes, int n_in,
                              void* d_out, int out_size, void* d_ws, size_t ws_size,
                              hipStream_t stream) {
  const float* x = (const float*)d_in[0];
  const int* lengths = (const int*)d_in[1];
  const float* weights = (const float*)d_in[2];
  const float* biases = (const float*)d_in[3];
  float* out = (float*)d_out;

  float* partials = (float*)d_ws;        // B*CHUNKS*2 floats = 16 KB total

  dim3 g1(CHUNKS, BB);                   // 2048 blocks
  setnorm_partials<<<g1, 256, 0, stream>>>(x, lengths, partials);
  setnorm_finalize<<<BB, 64, 0, stream>>>(lengths, partials);
  setnorm_norm<<<BB * K2_BPB, 256, 0, stream>>>(x, lengths, weights, biases,
                                                partials, out);
}